// Round 6
// baseline (339.697 us; speedup 1.0000x reference)
//
#include <hip/hip_runtime.h>

// Local NCC loss on (2,1,160,160,160) f32, 5x5x5 box window, SAME zero pad.
// Block 256 thr (4 waves), tile 32W x 32H x 8D, grid 1000 blocks (XCD-chunked
// swizzle: D-neighbor blocks share an XCD's L2 for the 4 halo slabs).
// Raw I/J staged in LDS (dbuf, +2-shifted, RST=44); each thread owns a 4-wide
// W strip: 20 ds_read_b128/slab -> vertical 5-sums of {I,J,I2,J2,IJ} -> hwin
// sliding W 5-window -> 5 compile-time D-phase f4 accumulators in registers.
// 12-slab loop fully unrolled: every phase index/guard is compile-time.

#define DIM 160
#define SLAB (DIM * DIM)
#define VOL (DIM * DIM * DIM)
#define TD 8
#define ROWS 36                   // staged H rows: 32 + 4 halo
#define RST 44                    // padded row stride (floats)
#define NBLK 1000
#define NPART (NBLK * 4)

typedef float f4 __attribute__((ext_vector_type(4), aligned(16)));
typedef float f2 __attribute__((ext_vector_type(2), aligned(8)));

__device__ __forceinline__ f4 hwin(const f4 lo, const f4 hi) {
    const float c0 = ((lo.x + lo.y) + (lo.z + lo.w)) + hi.x;
    const float c1 = c0 - lo.x + hi.y;
    const float c2 = c1 - lo.y + hi.z;
    const float c3 = c2 - lo.z + hi.w;
    return (f4){c0, c1, c2, c3};
}

__global__ __launch_bounds__(256, 2) void ncc_main(const float* __restrict__ real,
                                                   const float* __restrict__ fake,
                                                   float* __restrict__ partials) {
    __shared__ __align__(16) float raw[2][2][ROWS][RST];   // 25344 B

    const int tid = threadIdx.x;

    // XCD-chunked swizzle: xcd = bid&7 owns 125 consecutive tiles, D fastest.
    const int bid = blockIdx.x;
    const int g   = (bid & 7) * 125 + (bid >> 3);
    const int dz  = g % 20;
    const int t1  = g / 20;
    const int nb  = t1 & 1;
    const int t2  = t1 >> 1;               // 0..24
    const int bx  = t2 % 5;
    const int by  = t2 / 5;
    const int w0 = 32 * bx, h0 = 32 * by, d0 = TD * dz;

    const float* baseI = real + (size_t)nb * VOL;
    const float* baseJ = fake + (size_t)nb * VOL;

    // compute mapping: strip (sr=row 0..31, sc=0..7 -> w = w0+4sc..w0+4sc+3)
    const int sr = tid >> 3;
    const int sc = tid & 7;
    const int co = sr * RST + 4 * sc;

    // staging: 720 tasks = 2 vols x 36 rows x 10 quads; 3 per thread
    int gof[3], lof[3];
    bool ok[3], wlo[3];
    const float* src[3];
#pragma unroll
    for (int k = 0; k < 3; ++k) {
        const int t   = tid + 256 * k;
        const int tv  = t / 360;
        const int rem = t - 360 * tv;
        const int row = rem / 10;
        const int q   = rem - 10 * row;
        const int hg  = h0 - 2 + row;
        const int wq  = w0 - 4 + 4 * q;
        const bool okh = (unsigned)hg < DIM;
        const bool okw = (wq >= 0) && (wq + 3 < DIM);
        ok[k]  = (t < 720) && okh && okw;
        wlo[k] = ok[k] && (q > 0);
        gof[k] = hg * DIM + wq;
        lof[k] = (tv * ROWS + row) * RST + 4 * q - 2;
        src[k] = tv ? baseJ : baseI;
    }

    // zero LDS once (pads + D-edge slabs stay zero)
    {
        float* L = &raw[0][0][0][0];
        for (int i = tid; i < 2 * 2 * ROWS * RST; i += 256) L[i] = 0.f;
    }
    __syncthreads();

    // prologue: stage slab d0-2 into buf0 (d0==0 -> OOB, stays zero)
    if (d0 > 0) {
        const size_t so = (size_t)(d0 - 2) * SLAB;
        float* L = &raw[0][0][0][0];
#pragma unroll
        for (int k = 0; k < 3; ++k) {
            if (ok[k]) {
                const f4 v = *(const f4*)(src[k] + so + gof[k]);
                if (wlo[k]) *(f2*)(L + lof[k]) = (f2){v.x, v.y};
                *(f2*)(L + lof[k] + 2) = (f2){v.z, v.w};
            }
        }
    }
    __syncthreads();

    const f4 zf = (f4){0.f, 0.f, 0.f, 0.f};
    f4 zs[5][5];
#pragma unroll
    for (int p = 0; p < 5; ++p)
#pragma unroll
        for (int q = 0; q < 5; ++q) zs[p][q] = zf;

    f4 acc = zf;
    const float inv = 1.0f / 125.0f;

#pragma unroll
    for (int s = 0; s < 12; ++s) {         // slab dd = d0-2+s ; fully unrolled
        const int cur = s & 1;

        // ---- issue next-slab loads into registers ----
        f4 v0 = zf, v1 = zf, v2 = zf;
        if (s < 11) {
            const int dd1 = d0 - 1 + s;
            if ((unsigned)dd1 < DIM) {
                const size_t so = (size_t)dd1 * SLAB;
                if (ok[0]) v0 = *(const f4*)(src[0] + so + gof[0]);
                if (ok[1]) v1 = *(const f4*)(src[1] + so + gof[1]);
                if (ok[2]) v2 = *(const f4*)(src[2] + so + gof[2]);
            }
        }

        // ---- compute current slab: vertical 5-sums from 20 b128 reads ----
        const float* LI = &raw[cur][0][0][0];
        const float* LJ = &raw[cur][1][0][0];
        f4 vI0 = zf, vI1 = zf, vJ0 = zf, vJ1 = zf;
        f4 vI20 = zf, vI21 = zf, vJ20 = zf, vJ21 = zf, vIJ0 = zf, vIJ1 = zf;
#pragma unroll
        for (int t = 0; t < 5; ++t) {
            const int o = co + t * RST;
            const f4 a0 = *(const f4*)(LI + o);
            const f4 a1 = *(const f4*)(LI + o + 4);
            const f4 b0 = *(const f4*)(LJ + o);
            const f4 b1 = *(const f4*)(LJ + o + 4);
            vI0 += a0; vI1 += a1; vJ0 += b0; vJ1 += b1;
            vI20 += a0 * a0; vI21 += a1 * a1;
            vJ20 += b0 * b0; vJ21 += b1 * b1;
            vIJ0 += a0 * b0; vIJ1 += a1 * b1;
        }
        const f4 cs0 = hwin(vI0, vI1);
        const f4 cs1 = hwin(vJ0, vJ1);
        const f4 cs2 = hwin(vI20, vI21);
        const f4 cs3 = hwin(vJ20, vJ21);
        const f4 cs4 = hwin(vIJ0, vIJ1);

        // ---- add into active D-phases (all compile-time) ----
#pragma unroll
        for (int od = 0; od < TD; ++od) {
            if (od + 4 >= s && od <= s) {      // window slabs of od are od..od+4
                const int p = od % 5;
                zs[p][0] += cs0; zs[p][1] += cs1; zs[p][2] += cs2;
                zs[p][3] += cs3; zs[p][4] += cs4;
            }
        }

        // ---- completed output depth od = s-4 -> cc for 4 outputs ----
        if (s >= 4) {
            const int pe = (s - 4) % 5;        // compile-time
            const f4 SI = zs[pe][0], SJ = zs[pe][1];
            const f4 S2I = zs[pe][2], S2J = zs[pe][3], SIJ = zs[pe][4];
            const f4 t0    = SI * inv;
            const f4 cross = SIJ - t0 * SJ;
            const f4 iv    = S2I - t0 * SI;
            const f4 jv    = S2J - (SJ * inv) * SJ;
            acc += cross * cross / (iv * jv + 1e-5f);
            zs[pe][0] = zf; zs[pe][1] = zf; zs[pe][2] = zf;
            zs[pe][3] = zf; zs[pe][4] = zf;
        }

        // ---- write prefetched regs into other buffer ----
        if (s < 11) {
            float* L = &raw[cur ^ 1][0][0][0];
            if (wlo[0]) *(f2*)(L + lof[0]) = (f2){v0.x, v0.y};
            if (ok[0])  *(f2*)(L + lof[0] + 2) = (f2){v0.z, v0.w};
            if (wlo[1]) *(f2*)(L + lof[1]) = (f2){v1.x, v1.y};
            if (ok[1])  *(f2*)(L + lof[1] + 2) = (f2){v1.z, v1.w};
            if (wlo[2]) *(f2*)(L + lof[2]) = (f2){v2.x, v2.y};
            if (ok[2])  *(f2*)(L + lof[2] + 2) = (f2){v2.z, v2.w};
        }
        __syncthreads();
    }

    // ---- wave reduction -> one partial per wave ----
    float a2 = (acc.x + acc.y) + (acc.z + acc.w);
#pragma unroll
    for (int off = 32; off; off >>= 1)
        a2 += __shfl_down(a2, off, 64);
    if ((tid & 63) == 0)
        partials[bid * 4 + (tid >> 6)] = a2;
}

__global__ void ncc_reduce(const float* __restrict__ partials, float* __restrict__ out) {
    __shared__ double ws[4];
    double s = 0.0;
    for (int i = threadIdx.x; i < NPART; i += 256) s += (double)partials[i];
#pragma unroll
    for (int off = 32; off; off >>= 1)
        s += __shfl_down(s, off, 64);
    if ((threadIdx.x & 63) == 0) ws[threadIdx.x >> 6] = s;
    __syncthreads();
    if (threadIdx.x == 0) {
        const double t = ws[0] + ws[1] + ws[2] + ws[3];
        out[0] = (float)(t / (2.0 * (double)VOL));
    }
}

extern "C" void kernel_launch(void* const* d_in, const int* in_sizes, int n_in,
                              void* d_out, int out_size, void* d_ws, size_t ws_size,
                              hipStream_t stream) {
    const float* real = (const float*)d_in[0];
    const float* fake = (const float*)d_in[1];
    float* out      = (float*)d_out;
    float* partials = (float*)d_ws;   // NPART floats

    ncc_main<<<dim3(NBLK), dim3(256), 0, stream>>>(real, fake, partials);
    ncc_reduce<<<1, 256, 0, stream>>>(partials, out);
}

// Round 7
// 108.451 us; speedup vs baseline: 3.1323x; 3.1323x over previous
//
#include <hip/hip_runtime.h>

// Local NCC loss on (2,1,160,160,160) f32, 5x5x5 box window, SAME zero pad.
// Full-width design: block = 320 thr (5 waves), tile 160W x 8H x 8D, 800 blocks.
// Staging: global_load_lds 1KB chunks (LDS rows contiguous <-> global rows
// contiguous; no ds_write staging, no prefetch registers). Per-lane-clamped
// fallback for buffer-edge chunks; h-OOB rows zeroed by edge blocks; D-OOB
// slabs zero-filled. Compute: thread owns one f4 W-strip; 40 ds_read_b64/slab
// (consecutive-granule, conflict-free) -> vertical 5-sums of {I,J,I2,J2,IJ}
// in f2 regs -> hwin sliding W 5-window -> 5 compile-time D-phase f4 accums.
// amdgpu_waves_per_eu(2,2) pins VGPR budget to 256 so the backend cannot
// squeeze to 128-and-spill (R4/R6 failure mode). Outer loop unroll(1).

#define DIM 160
#define SLAB (DIM * DIM)          // 25600
#define VOL (DIM * DIM * DIM)     // 4096000
#define BUF 4104                  // floats/buffer: 4 guard + 2048 I + 2048 J + 4 guard
#define NBLK 800
#define NPART (NBLK * 5)

typedef float f4 __attribute__((ext_vector_type(4), aligned(16)));
typedef float f2 __attribute__((ext_vector_type(2), aligned(8)));

#define LD2(p) (*(const f2*)(p))

__device__ __forceinline__ void gl16(const float* g, float* l) {
    __builtin_amdgcn_global_load_lds(
        (const __attribute__((address_space(1))) void*)g,
        (__attribute__((address_space(3))) void*)l, 16, 0, 0);
}

__device__ __forceinline__ f4 hw8(const f2* v) {
    const float a0 = v[0].x, a1 = v[0].y, a2 = v[1].x, a3 = v[1].y,
                a4 = v[2].x, a5 = v[2].y, a6 = v[3].x, a7 = v[3].y;
    const float c0 = ((a0 + a1) + (a2 + a3)) + a4;
    const float c1 = c0 - a0 + a5;
    const float c2 = c1 - a1 + a6;
    const float c3 = c2 - a2 + a7;
    return (f4){c0, c1, c2, c3};
}

__global__ __launch_bounds__(320)
__attribute__((amdgpu_waves_per_eu(2, 2)))
void ncc_main(const float* __restrict__ real,
              const float* __restrict__ fake,
              float* __restrict__ partials) {
    __shared__ __align__(16) float L[2 * BUF];   // 32832 B

    const int tid  = threadIdx.x;
    const int lane = tid & 63;
    const int wid  = tid >> 6;

    // XCD-chunked swizzle: 8 chunks of 100, dz fastest within a chunk.
    const int bid = blockIdx.x;
    const int vid = (bid & 7) * 100 + (bid >> 3);
    const int dz  = vid % 20;
    const int by  = (vid / 20) % 20;
    const int nb  = vid / 400;
    const int h0 = 8 * by, d0 = 8 * dz;

    const float* baseI = real + (size_t)nb * VOL;
    const float* baseJ = fake + (size_t)nb * VOL;

    // compute mapping: thread -> (row r 0..7, f4 strip c 0..39), outputs w=4c..4c+3
    const int r = tid / 40;
    const int c = tid - 40 * r;

    const bool hedge = (by == 0) | (by == 19);
    const int  zr0   = (by == 0) ? 0 : 10;

    const f2 z2 = (f2){0.f, 0.f};
    const f4 zf = (f4){0.f, 0.f, 0.f, 0.f};

    // ---- stage slab dd into buffer bu ----
    auto stage = [&](int dd, int bu) {
        if ((unsigned)dd < DIM) {
            const int slabBase = dd * SLAB + (h0 - 2) * DIM;   // may be <0 at by==0,dd==0
            for (int k = wid; k < 16; k += 5) {
                const int vs = k >> 3, cc = k & 7;
                const float* vb = vs ? baseJ : baseI;
                const int src = slabBase + cc * 256;
                float* dst = L + bu * BUF + 4 + vs * 2048 + cc * 256;
                if (src >= 0 && src <= VOL - 256) {
                    gl16(vb + src + 4 * lane, dst);
                } else {
                    const int o = min(max(src + 4 * lane, 0), VOL - 4);
                    *(f4*)(dst + 4 * lane) = *(const f4*)(vb + o);
                }
            }
        } else {
            for (int i = tid; i < 960; i += 320) {
                const int off = (i < 480) ? (4 + 4 * i) : (2052 + 4 * (i - 480));
                *(f4*)(L + bu * BUF + off) = zf;
            }
        }
    };

    // ---- zero h-OOB rows of buffer bu (edge blocks only) ----
    auto zrows = [&](int bu) {
        if (tid < 160) {
            const int v  = tid / 80, rem = tid - 80 * v;
            const int rw = zr0 + rem / 40, gq = rem - 40 * (rem / 40);
            *(f4*)(L + bu * BUF + 4 + v * 2048 + rw * 160 + 4 * gq) = zf;
        }
    };

    // prologue: slab s=0 (dd=d0-2) -> buf0
    stage(d0 - 2, 0);
    __syncthreads();
    if (hedge) { zrows(0); __syncthreads(); }

    f4 zs[5][5];   // [phase][quantity], static indices only
#pragma unroll
    for (int p = 0; p < 5; ++p)
#pragma unroll
        for (int q = 0; q < 5; ++q) zs[p][q] = zf;

    f4 acc = zf;
    const float inv = 1.0f / 125.0f;
    int cur = 0;

#pragma unroll 1
    for (int a = 0; a < 3; ++a) {
#pragma unroll
        for (int b = 0; b < 5; ++b) {
            // s = 5a+b ; slabs 0..11 active, stage s+1 while s<11
            const bool compAct  = (a < 2) || (b < 2);
            const bool stageAct = (a < 2) || (b == 0);
            if (!compAct) continue;

            if (stageAct) stage(d0 - 1 + 5 * a + b, cur ^ 1);

            // ---- compute slab s from buf cur ----
            const float* pb = L + cur * BUF + 4 + (r * 160 + 4 * c - 2);
            f2 vA[4], vB[4], vA2[4], vB2[4], vAB[4];
#pragma unroll
            for (int j = 0; j < 4; ++j) {
                vA[j] = z2; vB[j] = z2; vA2[j] = z2; vB2[j] = z2; vAB[j] = z2;
            }
#pragma unroll
            for (int t = 0; t < 5; ++t) {
                const float* rp = pb + t * 160;
                f2 a0 = LD2(rp),        a1 = LD2(rp + 2),
                   a2 = LD2(rp + 4),    a3 = LD2(rp + 6);
                f2 b0 = LD2(rp + 2048), b1 = LD2(rp + 2050),
                   b2 = LD2(rp + 2052), b3 = LD2(rp + 2054);
                if (c == 0)  { a0 = z2; b0 = z2; }
                if (c == 39) { a3 = z2; b3 = z2; }
                vA[0] += a0; vA[1] += a1; vA[2] += a2; vA[3] += a3;
                vB[0] += b0; vB[1] += b1; vB[2] += b2; vB[3] += b3;
                vA2[0] += a0 * a0; vA2[1] += a1 * a1; vA2[2] += a2 * a2; vA2[3] += a3 * a3;
                vB2[0] += b0 * b0; vB2[1] += b1 * b1; vB2[2] += b2 * b2; vB2[3] += b3 * b3;
                vAB[0] += a0 * b0; vAB[1] += a1 * b1; vAB[2] += a2 * b2; vAB[3] += a3 * b3;
            }
            const f4 cs0 = hw8(vA);
            const f4 cs1 = hw8(vB);
            const f4 cs2 = hw8(vA2);
            const f4 cs3 = hw8(vB2);
            const f4 cs4 = hw8(vAB);

            // ---- add into active D-phases: od_p = s-((b-p)%5), need 0<=od_p<=7 ----
#pragma unroll
            for (int p = 0; p < 5; ++p) {
                const int kk  = (b - p + 5) % 5;   // compile-time
                const int bmk = b - kk;            // compile-time
                const bool doadd = (a > 0 || p <= b) &&
                                   (a == 0 || (a == 1 ? (bmk <= 2) : (bmk <= -3)));
                if (doadd) {
                    zs[p][0] += cs0; zs[p][1] += cs1; zs[p][2] += cs2;
                    zs[p][3] += cs3; zs[p][4] += cs4;
                }
            }

            // ---- completion: od = s-4 (4 <= s <= 11), phase pe = (b+1)%5 ----
            const bool docomp = (a == 0) ? (b == 4) : ((a == 1) ? true : (b < 2));
            if (docomp) {
                const int pe = (b + 1) % 5;        // compile-time
                const f4 SI = zs[pe][0], SJ = zs[pe][1];
                const f4 S2I = zs[pe][2], S2J = zs[pe][3], SIJ = zs[pe][4];
                const f4 t0    = SI * inv;
                const f4 cross = SIJ - t0 * SJ;
                const f4 iv    = S2I - t0 * SI;
                const f4 jv    = S2J - (SJ * inv) * SJ;
                acc += cross * cross / (iv * jv + 1e-5f);
                zs[pe][0] = zf; zs[pe][1] = zf; zs[pe][2] = zf;
                zs[pe][3] = zf; zs[pe][4] = zf;
            }

            __syncthreads();                        // slab s+1 loads landed
            if (hedge && stageAct) { zrows(cur ^ 1); __syncthreads(); }
            cur ^= 1;
        }
    }

    // ---- wave reduction -> one partial per wave ----
    float a2s = (acc.x + acc.y) + (acc.z + acc.w);
#pragma unroll
    for (int off = 32; off; off >>= 1)
        a2s += __shfl_down(a2s, off, 64);
    if (lane == 0)
        partials[bid * 5 + wid] = a2s;
}

__global__ void ncc_reduce(const float* __restrict__ partials, float* __restrict__ out) {
    __shared__ double ws[4];
    double s = 0.0;
    for (int i = threadIdx.x; i < NPART; i += 256) s += (double)partials[i];
#pragma unroll
    for (int off = 32; off; off >>= 1)
        s += __shfl_down(s, off, 64);
    if ((threadIdx.x & 63) == 0) ws[threadIdx.x >> 6] = s;
    __syncthreads();
    if (threadIdx.x == 0) {
        const double t = ws[0] + ws[1] + ws[2] + ws[3];
        out[0] = (float)(t / (2.0 * (double)VOL));
    }
}

extern "C" void kernel_launch(void* const* d_in, const int* in_sizes, int n_in,
                              void* d_out, int out_size, void* d_ws, size_t ws_size,
                              hipStream_t stream) {
    const float* real = (const float*)d_in[0];
    const float* fake = (const float*)d_in[1];
    float* out      = (float*)d_out;
    float* partials = (float*)d_ws;   // NPART floats

    ncc_main<<<dim3(NBLK), dim3(320), 0, stream>>>(real, fake, partials);
    ncc_reduce<<<1, 256, 0, stream>>>(partials, out);
}

// Round 8
// 53.275 us; speedup vs baseline: 6.3762x; 2.0357x over previous
//
#include <hip/hip_runtime.h>

// Local NCC loss on (2,1,160,160,160) f32, 5x5x5 box window, SAME zero pad.
// v5 dataflow + occupancy fix: block 256 thr (4 waves), tile 32W x 32H x 8D,
// grid 1000 blocks (3.9/CU; v5's 500 was grid-capped at 19% occupancy).
// XCD-chunked dz-fastest ordering: D-halo re-reads hit same-XCD L2 (v7 evidence).
// Raw I/J staged in LDS (dbuf, +2-shifted, RST=44); each thread owns a 4-wide
// W strip: 20 aligned ds_read_b128/slab -> vertical 5-sums of {I,J,I2,J2,IJ}
// -> hwin sliding W 5-window -> 5 compile-time D-phase f4 accumulators in
// registers. Outer a-loop pinned unroll(1): full unroll = R6's 658MB spill.

#define DIM 160
#define SLAB (DIM * DIM)
#define VOL (DIM * DIM * DIM)
#define TD 8
#define ROWS 36                   // staged H rows: 32 + 4 halo
#define RST 44                    // padded row stride (floats)
#define NBLK 1000
#define NPART (NBLK * 4)

typedef float f4 __attribute__((ext_vector_type(4), aligned(16)));
typedef float f2 __attribute__((ext_vector_type(2), aligned(8)));

__device__ __forceinline__ f4 hwin(const f4 lo, const f4 hi) {
    const float c0 = ((lo.x + lo.y) + (lo.z + lo.w)) + hi.x;
    const float c1 = c0 - lo.x + hi.y;
    const float c2 = c1 - lo.y + hi.z;
    const float c3 = c2 - lo.z + hi.w;
    return (f4){c0, c1, c2, c3};
}

__global__ __launch_bounds__(256, 2) void ncc_main(const float* __restrict__ real,
                                                   const float* __restrict__ fake,
                                                   float* __restrict__ partials) {
    __shared__ __align__(16) float raw[2][2][ROWS][RST];   // 25344 B

    const int tid = threadIdx.x;

    // XCD-chunked swizzle: chunk = bid&7 (8 chunks of 125), dz fastest inside.
    const int bid = blockIdx.x;
    const int vid = (bid & 7) * 125 + (bid >> 3);
    const int dz  = vid % 20;
    const int t1  = vid / 20;      // 0..49
    const int bx  = t1 % 5;
    const int by  = (t1 / 5) % 5;
    const int nb  = t1 / 25;
    const int w0 = 32 * bx, h0 = 32 * by, d0 = TD * dz;

    const float* baseI = real + (size_t)nb * VOL;
    const float* baseJ = fake + (size_t)nb * VOL;

    // compute mapping: strip (sr=row 0..31, sc=0..7 -> w = w0+4sc..w0+4sc+3)
    const int sr = tid >> 3;
    const int sc = tid & 7;
    const int co = sr * RST + 4 * sc;

    // staging: 720 tasks = 2 vols x 36 rows x 10 quads; 3 per thread
    int gof[3], lof[3];
    bool ok[3], wlo[3];
    const float* src[3];
#pragma unroll
    for (int k = 0; k < 3; ++k) {
        const int t   = tid + 256 * k;
        const int tv  = t / 360;
        const int rem = t - 360 * tv;
        const int row = rem / 10;
        const int q   = rem - 10 * row;
        const int hg  = h0 - 2 + row;
        const int wq  = w0 - 4 + 4 * q;
        const bool okh = (unsigned)hg < DIM;
        const bool okw = (wq >= 0) && (wq + 3 < DIM);
        ok[k]  = (t < 720) && okh && okw;
        wlo[k] = ok[k] && (q > 0);
        gof[k] = hg * DIM + wq;
        lof[k] = (tv * ROWS + row) * RST + 4 * q - 2;
        src[k] = tv ? baseJ : baseI;
    }

    // zero LDS once (pads + never-written halo slots stay zero)
    {
        float* L = &raw[0][0][0][0];
        for (int i = tid; i < 2 * 2 * ROWS * RST; i += 256) L[i] = 0.f;
    }
    __syncthreads();

    // prologue: stage slab d0-2 into buf0 (d0==0 -> OOB, stays zero)
    if (d0 > 0) {
        const size_t so = (size_t)(d0 - 2) * SLAB;
        float* L = &raw[0][0][0][0];
#pragma unroll
        for (int k = 0; k < 3; ++k) {
            if (ok[k]) {
                const f4 v = *(const f4*)(src[k] + so + gof[k]);
                if (wlo[k]) *(f2*)(L + lof[k]) = (f2){v.x, v.y};
                *(f2*)(L + lof[k] + 2) = (f2){v.z, v.w};
            }
        }
    }
    __syncthreads();

    const f4 zf = (f4){0.f, 0.f, 0.f, 0.f};
    f4 zs[5][5];                   // [phase][quantity], static indices only
#pragma unroll
    for (int p = 0; p < 5; ++p)
#pragma unroll
        for (int q = 0; q < 5; ++q) zs[p][q] = zf;

    f4 acc = zf;
    const float inv = 1.0f / 125.0f;
    int cur = 0;

#pragma unroll 1
    for (int a = 0; a < 3; ++a) {          // s = 5a+b, slabs 0..11
        const bool am0 = (a > 0);
#pragma unroll
        for (int b = 0; b < 5; ++b) {
            const bool compAct  = (a < 2) || (b < 2);   // s <= 11
            const bool stageAct = (a < 2) || (b == 0);  // s <= 10
            if (!compAct) continue;

            // ---- issue next-slab loads into registers ----
            f4 v0 = zf, v1 = zf, v2 = zf;
            if (stageAct) {
                const int dd1 = d0 - 1 + 5 * a + b;
                if ((unsigned)dd1 < DIM) {
                    const size_t so = (size_t)dd1 * SLAB;
                    if (ok[0]) v0 = *(const f4*)(src[0] + so + gof[0]);
                    if (ok[1]) v1 = *(const f4*)(src[1] + so + gof[1]);
                    if (ok[2]) v2 = *(const f4*)(src[2] + so + gof[2]);
                }
            }

            // ---- compute current slab: vertical 5-sums from 20 b128 reads ----
            const float* LI = &raw[cur][0][0][0];
            const float* LJ = &raw[cur][1][0][0];
            f4 vI0 = zf, vI1 = zf, vJ0 = zf, vJ1 = zf;
            f4 vI20 = zf, vI21 = zf, vJ20 = zf, vJ21 = zf, vIJ0 = zf, vIJ1 = zf;
#pragma unroll
            for (int t = 0; t < 5; ++t) {
                const int o = co + t * RST;
                const f4 a0 = *(const f4*)(LI + o);
                const f4 a1 = *(const f4*)(LI + o + 4);
                const f4 b0 = *(const f4*)(LJ + o);
                const f4 b1 = *(const f4*)(LJ + o + 4);
                vI0 += a0; vI1 += a1; vJ0 += b0; vJ1 += b1;
                vI20 += a0 * a0; vI21 += a1 * a1;
                vJ20 += b0 * b0; vJ21 += b1 * b1;
                vIJ0 += a0 * b0; vIJ1 += a1 * b1;
            }
            const f4 cs0 = hwin(vI0, vI1);
            const f4 cs1 = hwin(vJ0, vJ1);
            const f4 cs2 = hwin(vI20, vI21);
            const f4 cs3 = hwin(vJ20, vJ21);
            const f4 cs4 = hwin(vIJ0, vIJ1);

            // ---- add into active D-phases (guards uniform, indices static) ----
#pragma unroll
            for (int p = 0; p < 5; ++p) {
                const int kk  = (b - p + 5) % 5;   // compile-time
                const int bmk = b - kk;            // compile-time
                const bool doadd = (am0 || p <= b) &&
                                   (a == 0 || (a == 1 ? (bmk <= 2) : (bmk <= -3)));
                if (doadd) {
                    zs[p][0] += cs0; zs[p][1] += cs1; zs[p][2] += cs2;
                    zs[p][3] += cs3; zs[p][4] += cs4;
                }
            }

            // ---- completed output depth od = s-4 -> cc for 4 outputs ----
            const bool docomp = (a == 0) ? (b == 4) : ((a == 1) ? true : (b < 2));
            if (docomp) {
                const int pe = (b + 1) % 5;        // compile-time
                const f4 SI = zs[pe][0], SJ = zs[pe][1];
                const f4 S2I = zs[pe][2], S2J = zs[pe][3], SIJ = zs[pe][4];
                const f4 t0    = SI * inv;
                const f4 cross = SIJ - t0 * SJ;
                const f4 iv    = S2I - t0 * SI;
                const f4 jv    = S2J - (SJ * inv) * SJ;
                acc += cross * cross / (iv * jv + 1e-5f);
                zs[pe][0] = zf; zs[pe][1] = zf; zs[pe][2] = zf;
                zs[pe][3] = zf; zs[pe][4] = zf;
            }

            // ---- write prefetched regs into other buffer, flip ----
            if (stageAct) {
                float* L = &raw[cur ^ 1][0][0][0];
                if (wlo[0]) *(f2*)(L + lof[0]) = (f2){v0.x, v0.y};
                if (ok[0])  *(f2*)(L + lof[0] + 2) = (f2){v0.z, v0.w};
                if (wlo[1]) *(f2*)(L + lof[1]) = (f2){v1.x, v1.y};
                if (ok[1])  *(f2*)(L + lof[1] + 2) = (f2){v1.z, v1.w};
                if (wlo[2]) *(f2*)(L + lof[2]) = (f2){v2.x, v2.y};
                if (ok[2])  *(f2*)(L + lof[2] + 2) = (f2){v2.z, v2.w};
            }
            __syncthreads();
            cur ^= 1;
        }
    }

    // ---- wave reduction -> one partial per wave ----
    float a2 = (acc.x + acc.y) + (acc.z + acc.w);
#pragma unroll
    for (int off = 32; off; off >>= 1)
        a2 += __shfl_down(a2, off, 64);
    if ((tid & 63) == 0)
        partials[bid * 4 + (tid >> 6)] = a2;
}

__global__ void ncc_reduce(const float* __restrict__ partials, float* __restrict__ out) {
    __shared__ double ws[4];
    double s = 0.0;
    for (int i = threadIdx.x; i < NPART; i += 256) s += (double)partials[i];
#pragma unroll
    for (int off = 32; off; off >>= 1)
        s += __shfl_down(s, off, 64);
    if ((threadIdx.x & 63) == 0) ws[threadIdx.x >> 6] = s;
    __syncthreads();
    if (threadIdx.x == 0) {
        const double t = ws[0] + ws[1] + ws[2] + ws[3];
        out[0] = (float)(t / (2.0 * (double)VOL));
    }
}

extern "C" void kernel_launch(void* const* d_in, const int* in_sizes, int n_in,
                              void* d_out, int out_size, void* d_ws, size_t ws_size,
                              hipStream_t stream) {
    const float* real = (const float*)d_in[0];
    const float* fake = (const float*)d_in[1];
    float* out      = (float*)d_out;
    float* partials = (float*)d_ws;   // NPART floats

    ncc_main<<<dim3(NBLK), dim3(256), 0, stream>>>(real, fake, partials);
    ncc_reduce<<<1, 256, 0, stream>>>(partials, out);
}